// Round 5
// baseline (313.210 us; speedup 1.0000x reference)
//
#include <hip/hip_runtime.h>
#include <math.h>

// KGAT attention aggregation, MI355X.
// fc1->fc2 with no activation collapses to one linear functional; furthermore
// the ent-dot and bias are constant across the K neighbors and CANCEL in the
// softmax, so logits need only dot(ne_k,wne)+dot(nr_k,wnr) with w = W1@W2.
// R5: DPP-based reduction (4 VALU + 1 ds_swizzle per value, was 5 ds_swizzle),
//     5 reductions per row (was 6), no we/c loads. (ctrl as template imm.)

#define DIM 128
#define KN 5

typedef float nfloat4 __attribute__((ext_vector_type(4)));

__device__ __forceinline__ float dot4(nfloat4 a, nfloat4 b) {
    return a.x * b.x + a.y * b.y + a.z * b.z + a.w * b.w;
}

template <int CTRL>
__device__ __forceinline__ float dpp_add(float v) {
    int x = __builtin_amdgcn_update_dpp(0, __float_as_int(v), CTRL, 0xF, 0xF, true);
    return v + __int_as_float(x);
}

// Sum across a 32-lane half-wave; result in every lane of the half.
__device__ __forceinline__ float half_reduce(float v) {
    v = dpp_add<0xB1>(v);   // quad_perm {1,0,3,2}  : xor 1
    v = dpp_add<0x4E>(v);   // quad_perm {2,3,0,1}  : xor 2
    v = dpp_add<0x124>(v);  // row_ror:4
    v = dpp_add<0x128>(v);  // row_ror:8 -> 16-lane row sum in all lanes
    // cross-row within the half: xor 16 via ds_swizzle (BitMode 0x401F)
    v += __int_as_float(__builtin_amdgcn_ds_swizzle(__float_as_int(v), 0x401F));
    return v;
}

// w[t] = sum_a W1[128+t, a] * W2[a]  for t in [0,256): [wne | wnr].
// One wave per output element.
__global__ __launch_bounds__(256) void kgat_prep(
    const float* __restrict__ W1,   // [384,128]
    const float* __restrict__ W2,   // [128]
    float* __restrict__ ws)         // w[256]
{
    const int t = blockIdx.x * 4 + (threadIdx.x >> 6);
    const int lane = threadIdx.x & 63;
    if (t < 2 * DIM) {
        const float2 w1 = *(const float2*)(W1 + (size_t)(DIM + t) * DIM + 2 * lane);
        const float2 w2 = *(const float2*)(W2 + 2 * lane);
        float v = w1.x * w2.x + w1.y * w2.y;
        #pragma unroll
        for (int off = 32; off >= 1; off >>= 1) v += __shfl_xor(v, off, 64);
        if (lane == 0) ws[t] = v;
    }
}

// 32 lanes per (b,n) row; each wave handles 2 rows (half-waves independent).
__global__ __launch_bounds__(256) void kgat_main(
    const float* __restrict__ ent,   // [P, 128]
    const float* __restrict__ ne,    // [P, 5, 128]
    const float* __restrict__ nr,    // [P, 5, 128]
    const float* __restrict__ ws,    // wne[128], wnr[128]
    float* __restrict__ out,         // [P, 256]
    int P)
{
    const int wave = threadIdx.x >> 6;
    const int lane = threadIdx.x & 63;
    const int half = lane >> 5;        // which row within the wave
    const int l    = lane & 31;        // lane within the row
    const int p = blockIdx.x * 8 + wave * 2 + half;
    if (p >= P) return;

    const int d = l * 4;
    const nfloat4 wne = *(const nfloat4*)(ws + d);
    const nfloat4 wnr = *(const nfloat4*)(ws + DIM + d);

    const nfloat4 e4 = *(const nfloat4*)(ent + (size_t)p * DIM + d);
    const size_t rowK = ((size_t)p * KN) * DIM + d;
    nfloat4 ne4[KN], nr4[KN];
    #pragma unroll
    for (int k = 0; k < KN; ++k) {
        ne4[k] = *(const nfloat4*)(ne + rowK + (size_t)k * DIM);
        nr4[k] = *(const nfloat4*)(nr + rowK + (size_t)k * DIM);
    }

    // per-lane partials, then DPP reduction across the 32-lane half
    float logit[KN];
    #pragma unroll
    for (int k = 0; k < KN; ++k)
        logit[k] = half_reduce(dot4(ne4[k], wne) + dot4(nr4[k], wnr));

    // softmax over K=5 (ent-dot and bias are k-invariant: cancel)
    float m = -INFINITY;
    #pragma unroll
    for (int k = 0; k < KN; ++k) m = fmaxf(m, logit[k]);
    float ex[KN], s = 0.f;
    #pragma unroll
    for (int k = 0; k < KN; ++k) { ex[k] = __expf(logit[k] - m); s += ex[k]; }
    const float inv = 1.f / s;

    // attention-weighted neighbor sum from registers (no re-read of ne)
    nfloat4 acc = {0.f, 0.f, 0.f, 0.f};
    #pragma unroll
    for (int k = 0; k < KN; ++k) {
        const float a = ex[k] * inv;
        acc.x += a * ne4[k].x;
        acc.y += a * ne4[k].y;
        acc.z += a * ne4[k].z;
        acc.w += a * ne4[k].w;
    }

    float* orow = out + (size_t)p * (2 * DIM);
    __builtin_nontemporal_store(e4,  (nfloat4*)(orow + d));
    __builtin_nontemporal_store(acc, (nfloat4*)(orow + DIM + d));
}

extern "C" void kernel_launch(void* const* d_in, const int* in_sizes, int n_in,
                              void* d_out, int out_size, void* d_ws, size_t ws_size,
                              hipStream_t stream) {
    const float* ent = (const float*)d_in[0];
    const float* ne  = (const float*)d_in[1];
    const float* nr  = (const float*)d_in[2];
    const float* W1  = (const float*)d_in[3];
    const float* W2  = (const float*)d_in[5];
    float* out = (float*)d_out;
    float* ws  = (float*)d_ws;

    const int P = in_sizes[0] / DIM;  // B*N rows

    kgat_prep<<<(2 * DIM + 3) / 4, 256, 0, stream>>>(W1, W2, ws);
    kgat_main<<<(P + 7) / 8, 256, 0, stream>>>(ent, ne, nr, ws, out, P);
}